// Round 5
// baseline (480.889 us; speedup 1.0000x reference)
//
#include <hip/hip_runtime.h>
#include <cstdint>
#include <cstddef>

#define N_NODES 50000
#define N_EDGES 800000
#define IN_CH   64
#define OC      128   // HEADS*OUT_CH
#define HEADS   4
#define CH      32    // OUT_CH

#define NB      391        // dst buckets: 128 nodes each (d>>7)
#define BCAP    2560       // per-bucket capacity (mean 2046, +11 sigma)

#define SCAN_ITEMS  2048
#define SCAN_BLOCKS ((N_NODES + SCAN_ITEMS - 1) / SCAN_ITEMS)  // 25

static inline int ceil_div(int a, int b){ return (a + b - 1) / b; }

__device__ __forceinline__ float lrelu(float x){ return fmaxf(x, 0.2f * x); }

__device__ __forceinline__ unsigned pack_bf16(float x, float y){
  unsigned ux = __float_as_uint(x), uy = __float_as_uint(y);
  ux += 0x7FFFu + ((ux >> 16) & 1u);
  uy += 0x7FFFu + ((uy >> 16) & 1u);
  return (ux >> 16) | (uy & 0xFFFF0000u);
}

// ---- K1: histogram (dst degree + u8-packed (src,type) counts) + bucket scatter ----
__global__ __launch_bounds__(256) void k_histA(const int* __restrict__ ei,
                                               const int* __restrict__ et,
                                               int* __restrict__ cnt_dst,
                                               unsigned* __restrict__ cnt_nt,
                                               int* __restrict__ btail,
                                               unsigned* __restrict__ bbuf){
  int e = blockIdx.x * blockDim.x + threadIdx.x;
  if (e >= N_EDGES) return;
  int s = ei[e], d = ei[N_EDGES + e], t = et[e];
  atomicAdd(&cnt_dst[d], 1);
  atomicAdd(&cnt_nt[(size_t)s * 16 + (t >> 2)], 1u << (8 * (t & 3)));
  int b = d >> 7;
  int p = atomicAdd(&btail[b], 1);
  if (p < BCAP) bbuf[(size_t)b * BCAP + p] = ((unsigned)(d & 127) << 17) | (unsigned)s;
}

// ---- scan phase 1 ----
__global__ __launch_bounds__(256) void k_scan1(const int* __restrict__ cnt,
                                               int* __restrict__ bsum){
  int blk = blockIdx.x, tid = threadIdx.x;
  int base = blk * SCAN_ITEMS;
  int s = 0;
  #pragma unroll
  for (int j = 0; j < 8; ++j){
    int i = base + j * 256 + tid;
    if (i < N_NODES) s += cnt[i];
  }
  __shared__ int sbuf[256];
  sbuf[tid] = s; __syncthreads();
  for (int off = 128; off > 0; off >>= 1){
    if (tid < off) sbuf[tid] += sbuf[tid + off];
    __syncthreads();
  }
  if (tid == 0) bsum[blk] = sbuf[0];
}

// ---- scan phase 2: row_dst (exclusive at i+1) ----
__global__ __launch_bounds__(256) void k_scan2(const int* __restrict__ cnt,
                                               const int* __restrict__ bsum,
                                               int* __restrict__ row){
  int blk = blockIdx.x, tid = threadIdx.x;
  int base = blk * SCAN_ITEMS + tid * 8;

  __shared__ int sboff;
  if (tid == 0){
    int b = 0;
    for (int q = 0; q < blk; ++q) b += bsum[q];
    sboff = b;
  }
  int v[8];
  #pragma unroll
  for (int j = 0; j < 8; ++j){
    int i = base + j;
    v[j] = (i < N_NODES) ? cnt[i] : 0;
  }
  int pre[8]; int run = 0;
  #pragma unroll
  for (int j = 0; j < 8; ++j){ pre[j] = run; run += v[j]; }

  __shared__ int sbuf[256];
  sbuf[tid] = run; __syncthreads();
  for (int off = 1; off < 256; off <<= 1){
    int t = (tid >= off) ? sbuf[tid - off] : 0;
    __syncthreads();
    sbuf[tid] += t;
    __syncthreads();
  }
  int toff = sbuf[tid] - run;
  int boff = sboff;
  #pragma unroll
  for (int j = 0; j < 8; ++j){
    int i = base + j;
    if (i < N_NODES) row[i + 1] = boff + toff + pre[j] + v[j];
  }
  if (blk == 0 && tid == 0) row[0] = 0;
}

// ---- pass B: bucket -> final CSR list (dense contiguous writes) ----
__global__ __launch_bounds__(256) void k_passB(const unsigned* __restrict__ bbuf,
                                               const int* __restrict__ btail,
                                               const int* __restrict__ row,
                                               int* __restrict__ lst){
  int b = blockIdx.x, tid = threadIdx.x;
  int d0 = b << 7;
  int nn = min(128, N_NODES - d0);
  __shared__ int cur[128];
  __shared__ int g0;
  if (tid == 0) g0 = row[d0];
  if (tid < nn) cur[tid] = row[d0 + tid];
  __syncthreads();
  int base0 = g0;
  if (tid < nn) cur[tid] -= base0;   // bucket-local cursor
  __syncthreads();
  int cnt_b = min(btail[b], BCAP);
  for (int i = tid; i < cnt_b; i += 256){
    unsigned ent = bbuf[(size_t)b * BCAP + i];
    int doff = ent >> 17;
    int src  = ent & 0x1FFFF;
    int p = atomicAdd(&cur[doff], 1);
    lst[base0 + p] = src;
  }
}

// ---- peW = pe @ W ----
__global__ __launch_bounds__(256) void k_prep(const float* __restrict__ pe,
                                              const float* __restrict__ W,
                                              float* __restrict__ peW){
  __shared__ float sPe[64 * 64];
  int tid = threadIdx.x;
  for (int i = tid; i < 64 * 64 / 4; i += 256)
    ((float4*)sPe)[i] = ((const float4*)pe)[i];
  __syncthreads();
  int c = tid & 127, rb = tid >> 7;
  for (int k = 0; k < 32; ++k){
    int t = rb + 2 * k;
    float a = 0.f;
    #pragma unroll
    for (int i = 0; i < 64; ++i) a += sPe[t * 64 + i] * W[i * 128 + c];
    peW[t * 128 + c] = a;
  }
}

// ---- fused GEMM: xl = x @ W + f32(cnt_nt) @ peW  -> staged in d_out (f32) ----
#define GROWS 32
__global__ __launch_bounds__(256) void k_gemm_fused(const float* __restrict__ x,
                                                    const unsigned* __restrict__ cnt_nt,
                                                    const float* __restrict__ W,
                                                    const float* __restrict__ peW,
                                                    float* __restrict__ xl){
  __shared__ float sW[64 * 128];   // 32 KB
  __shared__ float sX[GROWS * 64]; // 8 KB
  int tid = threadIdx.x;
  int row0 = blockIdx.x * GROWS;
  int c = tid & 127, rb = tid >> 7;
  float acc[16];
  #pragma unroll
  for (int k = 0; k < 16; ++k) acc[k] = 0.f;

  // phase 0: x @ W
  for (int i = tid; i < 64 * 128 / 4; i += 256)
    ((float4*)sW)[i] = ((const float4*)W)[i];
  for (int i = tid; i < GROWS * 64 / 4; i += 256){
    int r = i >> 4;
    float4 v = make_float4(0.f, 0.f, 0.f, 0.f);
    if (row0 + r < N_NODES)
      v = ((const float4*)(x + (size_t)row0 * 64))[i];
    ((float4*)sX)[i] = v;
  }
  __syncthreads();
  #pragma unroll 1
  for (int k = 0; k < 16; ++k){
    int r = rb + 2 * k;
    float a = 0.f;
    #pragma unroll
    for (int i = 0; i < 64; ++i) a += sX[r * 64 + i] * sW[i * 128 + c];
    acc[k] += a;
  }
  __syncthreads();

  // phase 1: f32(u8 counts) @ peW
  for (int i = tid; i < 64 * 128 / 4; i += 256)
    ((float4*)sW)[i] = ((const float4*)peW)[i];
  for (int i = tid; i < GROWS * 16; i += 256){
    int r = i >> 4, j = i & 15;
    unsigned wv = 0;
    if (row0 + r < N_NODES) wv = cnt_nt[(size_t)(row0 + r) * 16 + j];
    sX[r * 64 + 4 * j]     = (float)(wv & 0xFFu);
    sX[r * 64 + 4 * j + 1] = (float)((wv >> 8) & 0xFFu);
    sX[r * 64 + 4 * j + 2] = (float)((wv >> 16) & 0xFFu);
    sX[r * 64 + 4 * j + 3] = (float)(wv >> 24);
  }
  __syncthreads();
  #pragma unroll 1
  for (int k = 0; k < 16; ++k){
    int r = rb + 2 * k;
    float a = 0.f;
    #pragma unroll
    for (int i = 0; i < 64; ++i) a += sX[r * 64 + i] * sW[i * 128 + c];
    acc[k] += a;
  }
  #pragma unroll
  for (int k = 0; k < 16; ++k){
    int r = rb + 2 * k;
    if (row0 + r < N_NODES) xl[(size_t)(row0 + r) * 128 + c] = acc[k];
  }
}

// ---- post-GEMM: a_src/a_dst (shfl reduce) + bf16 pack of xl (wave per node) ----
__global__ __launch_bounds__(256) void k_postgemm(const float* __restrict__ xl,
                                                  const float* __restrict__ as,
                                                  const float* __restrict__ ad,
                                                  float* __restrict__ a_src,
                                                  float* __restrict__ a_dst,
                                                  unsigned* __restrict__ xh){
  int n = (blockIdx.x * blockDim.x + threadIdx.x) >> 6;
  if (n >= N_NODES) return;
  int l = threadIdx.x & 63;
  float2 v  = ((const float2*)xl)[(size_t)n * 64 + l];
  float2 af = ((const float2*)as)[l];
  float2 df = ((const float2*)ad)[l];
  float ps = v.x * af.x + v.y * af.y;
  float pd = v.x * df.x + v.y * df.y;
  #pragma unroll
  for (int m = 1; m < 16; m <<= 1){
    ps += __shfl_xor(ps, m);
    pd += __shfl_xor(pd, m);
  }
  xh[(size_t)n * 64 + l] = pack_bf16(v.x, v.y);
  if ((l & 15) == 0){
    int h = l >> 4;
    a_src[n * 4 + h] = ps;
    a_dst[n * 4 + h] = pd;
  }
}

// ---- fused aggregate: exp (no max), weighted sum, bias+ELU (wave per node) ----
// lane l owns channels (2l, 2l+1) as bf16x2; head h = l>>4.
__global__ __launch_bounds__(256) void k_aggregate(const int* __restrict__ row_dst,
                                                   const int* __restrict__ lst,
                                                   const float* __restrict__ a_src,
                                                   const float* __restrict__ a_dst,
                                                   const unsigned* __restrict__ xh,
                                                   const float* __restrict__ bias,
                                                   float* __restrict__ out){
  int n = (blockIdx.x * blockDim.x + threadIdx.x) >> 6;
  if (n >= N_NODES) return;
  int l = threadIdx.x & 63;
  int h = l >> 4;
  float ad = a_dst[n * 4 + h];

  // self loop
  float w = __expf(lrelu(a_src[n * 4 + h] + ad));
  unsigned uv = xh[(size_t)n * 64 + l];
  float l0 = w, l1 = 0.f;
  float a0x = w * __uint_as_float(uv << 16);
  float a0y = w * __uint_as_float(uv & 0xFFFF0000u);
  float a1x = 0.f, a1y = 0.f;

  int k0 = row_dst[n], k1 = row_dst[n + 1];
  for (int kb = k0; kb < k1; kb += 64){
    int rem = k1 - kb;
    int nk = rem < 64 ? rem : 64;
    int sj = lst[(kb + l < k1) ? kb + l : k1 - 1];   // coalesced batch
    int sA = __shfl(sj, 0);
    int sB = __shfl(sj, nk > 1 ? 1 : 0);
    unsigned uA = xh[(size_t)sA * 64 + l]; float aA = a_src[sA * 4 + h];
    unsigned uB = xh[(size_t)sB * 64 + l]; float aB = a_src[sB * 4 + h];
    for (int j = 0; j < nk; j += 2){
      int pA = j + 2 < nk ? j + 2 : nk - 1;
      int pB = j + 3 < nk ? j + 3 : nk - 1;
      int sA2 = __shfl(sj, pA);
      int sB2 = __shfl(sj, pB);
      unsigned uA2 = xh[(size_t)sA2 * 64 + l]; float aA2 = a_src[sA2 * 4 + h];
      unsigned uB2 = xh[(size_t)sB2 * 64 + l]; float aB2 = a_src[sB2 * 4 + h];
      float wA = __expf(lrelu(aA + ad));
      l0 += wA;
      a0x = fmaf(wA, __uint_as_float(uA << 16), a0x);
      a0y = fmaf(wA, __uint_as_float(uA & 0xFFFF0000u), a0y);
      if (j + 1 < nk){
        float wB = __expf(lrelu(aB + ad));
        l1 += wB;
        a1x = fmaf(wB, __uint_as_float(uB << 16), a1x);
        a1y = fmaf(wB, __uint_as_float(uB & 0xFFFF0000u), a1y);
      }
      uA = uA2; aA = aA2; uB = uB2; aB = aB2;
    }
  }
  float lsum = l0 + l1;
  float accx = a0x + a1x;
  float accy = a0y + a1y;
  float2 b = ((const float2*)bias)[l];
  float r0 = accx / lsum + b.x;
  float r1 = accy / lsum + b.y;
  float2 o;
  o.x = r0 > 0.f ? r0 : expm1f(r0);
  o.y = r1 > 0.f ? r1 : expm1f(r1);
  ((float2*)out)[(size_t)n * 64 + l] = o;
}

extern "C" void kernel_launch(void* const* d_in, const int* in_sizes, int n_in,
                              void* d_out, int out_size, void* d_ws, size_t ws_size,
                              hipStream_t stream){
  const float* x     = (const float*)d_in[0];
  const int*   ei    = (const int*)d_in[1];   // [2, E]
  const int*   et    = (const int*)d_in[2];   // [E]
  const float* pe    = (const float*)d_in[3];
  const float* W     = (const float*)d_in[4];
  const float* att_s = (const float*)d_in[5];
  const float* att_d = (const float*)d_in[6];
  const float* bias  = (const float*)d_in[7];
  float* out = (float*)d_out;

  // workspace carve-up (all 4-byte units).
  // [cnt_dst | cnt_nt | btail] contiguous -> single memset.
  int*      cnt_dst = (int*)d_ws;                                  // N
  unsigned* cnt_nt  = (unsigned*)(cnt_dst + N_NODES);              // N*16 (u8 packed)
  int*      btail   = (int*)(cnt_nt + (size_t)N_NODES * 16);       // NB (pad 512)
  int*      row_dst = btail + 512;                                 // N+1 (pad)
  int*      bsum    = row_dst + N_NODES + 8;                       // 32
  float*    peW     = (float*)(bsum + 32);                         // 64*128
  float*    a_src   = peW + 64 * 128;                              // N*4
  float*    a_dst   = a_src + (size_t)N_NODES * 4;                 // N*4
  unsigned* xh      = (unsigned*)(a_dst + (size_t)N_NODES * 4);    // N*64 (bf16x2)
  unsigned* bbuf    = xh + (size_t)N_NODES * 64;                   // NB*BCAP
  int*      lst     = (int*)(bbuf + (size_t)NB * BCAP);            // E

  float* xl_stage = out;  // stage f32 xl in d_out; overwritten by k_aggregate

  const int B = 256;

  hipMemsetAsync(cnt_dst, 0, ((size_t)N_NODES * 17 + 512) * sizeof(int), stream);
  k_prep<<<1, B, 0, stream>>>(pe, W, peW);
  k_histA<<<ceil_div(N_EDGES, B), B, 0, stream>>>(ei, et, cnt_dst, cnt_nt, btail, bbuf);
  k_scan1<<<SCAN_BLOCKS, B, 0, stream>>>(cnt_dst, bsum);
  k_scan2<<<SCAN_BLOCKS, B, 0, stream>>>(cnt_dst, bsum, row_dst);
  k_passB<<<NB, B, 0, stream>>>(bbuf, btail, row_dst, lst);
  k_gemm_fused<<<ceil_div(N_NODES, GROWS), B, 0, stream>>>(x, cnt_nt, W, peW, xl_stage);
  k_postgemm<<<ceil_div(N_NODES * 64, B), B, 0, stream>>>(xl_stage, att_s, att_d,
                                                          a_src, a_dst, xh);
  k_aggregate<<<ceil_div(N_NODES * 64, B), B, 0, stream>>>(row_dst, lst, a_src, a_dst,
                                                           xh, bias, out);
}

// Round 6
// 194.518 us; speedup vs baseline: 2.4722x; 2.4722x over previous
//
#include <hip/hip_runtime.h>
#include <cstdint>
#include <cstddef>

#define N_NODES 50000
#define N_EDGES 800000
#define IN_CH   64
#define OC      128   // HEADS*OUT_CH
#define HEADS   4
#define CH      32    // OUT_CH

#define NB      391        // dst buckets: 128 nodes each (d>>7)
#define BCAP    2560       // per-bucket capacity (mean 2046, +11 sigma)
#define EPB     4096       // edges per histA block (256 threads x 16)
#define HIST_BLOCKS ((N_EDGES + EPB - 1) / EPB)   // 196

#define SCAN_ITEMS  2048
#define SCAN_BLOCKS ((N_NODES + SCAN_ITEMS - 1) / SCAN_ITEMS)  // 25

static inline int ceil_div(int a, int b){ return (a + b - 1) / b; }

__device__ __forceinline__ float lrelu(float x){ return fmaxf(x, 0.2f * x); }

__device__ __forceinline__ unsigned pack_bf16(float x, float y){
  unsigned ux = __float_as_uint(x), uy = __float_as_uint(y);
  ux += 0x7FFFu + ((ux >> 16) & 1u);
  uy += 0x7FFFu + ((uy >> 16) & 1u);
  return (ux >> 16) | (uy & 0xFFFF0000u);   // low16 = x, high16 = y
}

// ---- K1: cnt_nt atomics + block-aggregated bucket scatter ----
// entry = (b<<23) | (doff<<16) | src   (b<512, doff<128, src<65536)
__global__ __launch_bounds__(256) void k_histA(const int* __restrict__ ei,
                                               const int* __restrict__ et,
                                               unsigned* __restrict__ cnt_nt,
                                               int* __restrict__ btail,
                                               unsigned* __restrict__ bbuf){
  __shared__ int cnt[NB + 1];
  __shared__ int pos[NB + 1];
  int tid = threadIdx.x;
  for (int i = tid; i <= NB; i += 256){ cnt[i] = 0; }
  __syncthreads();

  int e0 = blockIdx.x * EPB;
  unsigned ent[16];
  #pragma unroll
  for (int j = 0; j < 16; ++j){
    int e = e0 + j * 256 + tid;
    ent[j] = 0xFFFFFFFFu;
    if (e < N_EDGES){
      int s = ei[e], d = ei[N_EDGES + e], t = et[e];
      atomicAdd(&cnt_nt[(size_t)s * 16 + (t >> 2)], 1u << (8 * (t & 3)));
      int b = d >> 7;
      ent[j] = ((unsigned)b << 23) | ((unsigned)(d & 127) << 16) | (unsigned)s;
      atomicAdd(&cnt[b], 1);
    }
  }
  __syncthreads();
  // reserve contiguous ranges per touched bucket
  for (int i = tid; i < NB; i += 256){
    int c = cnt[i];
    pos[i] = c ? atomicAdd(&btail[i], c) : 0;
  }
  __syncthreads();
  #pragma unroll
  for (int j = 0; j < 16; ++j){
    if (ent[j] != 0xFFFFFFFFu){
      int b = ent[j] >> 23;
      int p = atomicAdd(&pos[b], 1);
      if (p < BCAP) bbuf[(size_t)b * BCAP + p] = ent[j];
    }
  }
}

// ---- per-bucket node-degree counts (replaces global cnt_dst atomics) ----
__global__ __launch_bounds__(256) void k_passB_count(const unsigned* __restrict__ bbuf,
                                                     const int* __restrict__ btail,
                                                     int* __restrict__ cnt_dst){
  int b = blockIdx.x, tid = threadIdx.x;
  int d0 = b << 7;
  int nn = min(128, N_NODES - d0);
  __shared__ int c[128];
  if (tid < 128) c[tid] = 0;
  __syncthreads();
  int cnt_b = min(btail[b], BCAP);
  for (int i = tid; i < cnt_b; i += 256){
    unsigned ent = bbuf[(size_t)b * BCAP + i];
    atomicAdd(&c[(ent >> 16) & 127], 1);
  }
  __syncthreads();
  if (tid < nn) cnt_dst[d0 + tid] = c[tid];
}

// ---- scan phase 1 ----
__global__ __launch_bounds__(256) void k_scan1(const int* __restrict__ cnt,
                                               int* __restrict__ bsum){
  int blk = blockIdx.x, tid = threadIdx.x;
  int base = blk * SCAN_ITEMS;
  int s = 0;
  #pragma unroll
  for (int j = 0; j < 8; ++j){
    int i = base + j * 256 + tid;
    if (i < N_NODES) s += cnt[i];
  }
  __shared__ int sbuf[256];
  sbuf[tid] = s; __syncthreads();
  for (int off = 128; off > 0; off >>= 1){
    if (tid < off) sbuf[tid] += sbuf[tid + off];
    __syncthreads();
  }
  if (tid == 0) bsum[blk] = sbuf[0];
}

// ---- scan phase 2: row_dst (exclusive at i+1) ----
__global__ __launch_bounds__(256) void k_scan2(const int* __restrict__ cnt,
                                               const int* __restrict__ bsum,
                                               int* __restrict__ row){
  int blk = blockIdx.x, tid = threadIdx.x;
  int base = blk * SCAN_ITEMS + tid * 8;

  __shared__ int sboff;
  if (tid == 0){
    int b = 0;
    for (int q = 0; q < blk; ++q) b += bsum[q];
    sboff = b;
  }
  int v[8];
  #pragma unroll
  for (int j = 0; j < 8; ++j){
    int i = base + j;
    v[j] = (i < N_NODES) ? cnt[i] : 0;
  }
  int pre[8]; int run = 0;
  #pragma unroll
  for (int j = 0; j < 8; ++j){ pre[j] = run; run += v[j]; }

  __shared__ int sbuf[256];
  sbuf[tid] = run; __syncthreads();
  for (int off = 1; off < 256; off <<= 1){
    int t = (tid >= off) ? sbuf[tid - off] : 0;
    __syncthreads();
    sbuf[tid] += t;
    __syncthreads();
  }
  int toff = sbuf[tid] - run;
  int boff = sboff;
  #pragma unroll
  for (int j = 0; j < 8; ++j){
    int i = base + j;
    if (i < N_NODES) row[i + 1] = boff + toff + pre[j] + v[j];
  }
  if (blk == 0 && tid == 0) row[0] = 0;
}

// ---- bucket -> final CSR list (dense contiguous writes per bucket) ----
__global__ __launch_bounds__(256) void k_passB_write(const unsigned* __restrict__ bbuf,
                                                     const int* __restrict__ btail,
                                                     const int* __restrict__ row,
                                                     int* __restrict__ lst){
  int b = blockIdx.x, tid = threadIdx.x;
  int d0 = b << 7;
  int nn = min(128, N_NODES - d0);
  __shared__ int cur[128];
  __shared__ int g0;
  if (tid == 0) g0 = row[d0];
  __syncthreads();
  int base0 = g0;
  if (tid < nn) cur[tid] = row[d0 + tid] - base0;
  __syncthreads();
  int cnt_b = min(btail[b], BCAP);
  for (int i = tid; i < cnt_b; i += 256){
    unsigned ent = bbuf[(size_t)b * BCAP + i];
    int doff = (ent >> 16) & 127;
    int src  = ent & 0xFFFF;
    int p = atomicAdd(&cur[doff], 1);
    lst[base0 + p] = src;
  }
}

// ---- peW = pe @ W ----
__global__ __launch_bounds__(256) void k_prep(const float* __restrict__ pe,
                                              const float* __restrict__ W,
                                              float* __restrict__ peW){
  __shared__ float sPe[64 * 64];
  int tid = threadIdx.x;
  for (int i = tid; i < 64 * 64 / 4; i += 256)
    ((float4*)sPe)[i] = ((const float4*)pe)[i];
  __syncthreads();
  int c = tid & 127, rb = tid >> 7;
  for (int k = 0; k < 32; ++k){
    int t = rb + 2 * k;
    float a = 0.f;
    #pragma unroll
    for (int i = 0; i < 64; ++i) a += sPe[t * 64 + i] * W[i * 128 + c];
    peW[t * 128 + c] = a;
  }
}

// ---- fused GEMM + epilogue: xl = x@W + f32(cnt_nt)@peW; emits bf16 xh + a_src/a_dst ----
#define GROWS 32
__global__ __launch_bounds__(256) void k_gemm_fused(const float* __restrict__ x,
                                                    const unsigned* __restrict__ cnt_nt,
                                                    const float* __restrict__ W,
                                                    const float* __restrict__ peW,
                                                    const float* __restrict__ att_s,
                                                    const float* __restrict__ att_d,
                                                    float* __restrict__ a_src,
                                                    float* __restrict__ a_dst,
                                                    unsigned* __restrict__ xh){
  __shared__ float sW[64 * 128];   // 32 KB
  __shared__ float sX[GROWS * 64]; // 8 KB
  int tid = threadIdx.x;
  int row0 = blockIdx.x * GROWS;
  int c = tid & 127, rb = tid >> 7;
  float acc[16];
  #pragma unroll
  for (int k = 0; k < 16; ++k) acc[k] = 0.f;

  // phase 0: x @ W
  for (int i = tid; i < 64 * 128 / 4; i += 256)
    ((float4*)sW)[i] = ((const float4*)W)[i];
  for (int i = tid; i < GROWS * 64 / 4; i += 256){
    int r = i >> 4;
    float4 v = make_float4(0.f, 0.f, 0.f, 0.f);
    if (row0 + r < N_NODES)
      v = ((const float4*)(x + (size_t)row0 * 64))[i];
    ((float4*)sX)[i] = v;
  }
  __syncthreads();
  #pragma unroll 1
  for (int k = 0; k < 16; ++k){
    int r = rb + 2 * k;
    float a = 0.f;
    #pragma unroll
    for (int i = 0; i < 64; ++i) a += sX[r * 64 + i] * sW[i * 128 + c];
    acc[k] += a;
  }
  __syncthreads();

  // phase 1: f32(u8 counts) @ peW
  for (int i = tid; i < 64 * 128 / 4; i += 256)
    ((float4*)sW)[i] = ((const float4*)peW)[i];
  for (int i = tid; i < GROWS * 16; i += 256){
    int r = i >> 4, j = i & 15;
    unsigned wv = 0;
    if (row0 + r < N_NODES) wv = cnt_nt[(size_t)(row0 + r) * 16 + j];
    sX[r * 64 + 4 * j]     = (float)(wv & 0xFFu);
    sX[r * 64 + 4 * j + 1] = (float)((wv >> 8) & 0xFFu);
    sX[r * 64 + 4 * j + 2] = (float)((wv >> 16) & 0xFFu);
    sX[r * 64 + 4 * j + 3] = (float)(wv >> 24);
  }
  __syncthreads();
  #pragma unroll 1
  for (int k = 0; k < 16; ++k){
    int r = rb + 2 * k;
    float a = 0.f;
    #pragma unroll
    for (int i = 0; i < 64; ++i) a += sX[r * 64 + i] * sW[i * 128 + c];
    acc[k] += a;
  }

  // epilogue: attention dots (32-lane shfl reduce) + bf16 pack
  float asc = att_s[c], adc = att_d[c];
  int h = c >> 5;
  #pragma unroll 1
  for (int k = 0; k < 16; ++k){
    int r = rb + 2 * k;
    int n = row0 + r;
    bool valid = n < N_NODES;
    float ps = acc[k] * asc;
    float pd = acc[k] * adc;
    #pragma unroll
    for (int m = 1; m < 32; m <<= 1){
      ps += __shfl_xor(ps, m);
      pd += __shfl_xor(pd, m);
    }
    float other = __shfl_xor(acc[k], 1);
    if (valid){
      if ((c & 31) == 0){
        a_src[n * 4 + h] = ps;
        a_dst[n * 4 + h] = pd;
      }
      if (!(c & 1))
        xh[(size_t)n * 64 + (c >> 1)] = pack_bf16(acc[k], other);
    }
  }
}

// ---- fused aggregate: exp (no max), weighted sum, bias+ELU (wave per node) ----
// lane l owns channels (2l, 2l+1) as bf16x2; head h = l>>4.
__global__ __launch_bounds__(256) void k_aggregate(const int* __restrict__ row_dst,
                                                   const int* __restrict__ lst,
                                                   const float* __restrict__ a_src,
                                                   const float* __restrict__ a_dst,
                                                   const unsigned* __restrict__ xh,
                                                   const float* __restrict__ bias,
                                                   float* __restrict__ out){
  int n = (blockIdx.x * blockDim.x + threadIdx.x) >> 6;
  if (n >= N_NODES) return;
  int l = threadIdx.x & 63;
  int h = l >> 4;
  float ad = a_dst[n * 4 + h];

  // self loop
  float w = __expf(lrelu(a_src[n * 4 + h] + ad));
  unsigned uv = xh[(size_t)n * 64 + l];
  float l0 = w, l1 = 0.f;
  float a0x = w * __uint_as_float(uv << 16);
  float a0y = w * __uint_as_float(uv & 0xFFFF0000u);
  float a1x = 0.f, a1y = 0.f;

  int k0 = row_dst[n], k1 = row_dst[n + 1];
  for (int kb = k0; kb < k1; kb += 64){
    int rem = k1 - kb;
    int nk = rem < 64 ? rem : 64;
    int sj = lst[(kb + l < k1) ? kb + l : k1 - 1];   // coalesced batch
    int sA = __shfl(sj, 0);
    int sB = __shfl(sj, nk > 1 ? 1 : 0);
    unsigned uA = xh[(size_t)sA * 64 + l]; float aA = a_src[sA * 4 + h];
    unsigned uB = xh[(size_t)sB * 64 + l]; float aB = a_src[sB * 4 + h];
    for (int j = 0; j < nk; j += 2){
      int pA = j + 2 < nk ? j + 2 : nk - 1;
      int pB = j + 3 < nk ? j + 3 : nk - 1;
      int sA2 = __shfl(sj, pA);
      int sB2 = __shfl(sj, pB);
      unsigned uA2 = xh[(size_t)sA2 * 64 + l]; float aA2 = a_src[sA2 * 4 + h];
      unsigned uB2 = xh[(size_t)sB2 * 64 + l]; float aB2 = a_src[sB2 * 4 + h];
      float wA = __expf(lrelu(aA + ad));
      l0 += wA;
      a0x = fmaf(wA, __uint_as_float(uA << 16), a0x);
      a0y = fmaf(wA, __uint_as_float(uA & 0xFFFF0000u), a0y);
      if (j + 1 < nk){
        float wB = __expf(lrelu(aB + ad));
        l1 += wB;
        a1x = fmaf(wB, __uint_as_float(uB << 16), a1x);
        a1y = fmaf(wB, __uint_as_float(uB & 0xFFFF0000u), a1y);
      }
      uA = uA2; aA = aA2; uB = uB2; aB = aB2;
    }
  }
  float lsum = l0 + l1;
  float accx = a0x + a1x;
  float accy = a0y + a1y;
  float2 b = ((const float2*)bias)[l];
  float r0 = accx / lsum + b.x;
  float r1 = accy / lsum + b.y;
  float2 o;
  o.x = r0 > 0.f ? r0 : expm1f(r0);
  o.y = r1 > 0.f ? r1 : expm1f(r1);
  ((float2*)out)[(size_t)n * 64 + l] = o;
}

extern "C" void kernel_launch(void* const* d_in, const int* in_sizes, int n_in,
                              void* d_out, int out_size, void* d_ws, size_t ws_size,
                              hipStream_t stream){
  const float* x     = (const float*)d_in[0];
  const int*   ei    = (const int*)d_in[1];   // [2, E]
  const int*   et    = (const int*)d_in[2];   // [E]
  const float* pe    = (const float*)d_in[3];
  const float* W     = (const float*)d_in[4];
  const float* att_s = (const float*)d_in[5];
  const float* att_d = (const float*)d_in[6];
  const float* bias  = (const float*)d_in[7];
  float* out = (float*)d_out;

  // workspace carve-up (4-byte units). [cnt_nt | btail] contiguous -> one memset.
  unsigned* cnt_nt  = (unsigned*)d_ws;                             // N*16 (u8 packed)
  int*      btail   = (int*)(cnt_nt + (size_t)N_NODES * 16);       // NB (pad 512)
  int*      cnt_dst = btail + 512;                                 // N
  int*      row_dst = cnt_dst + N_NODES;                           // N+1 (pad 8)
  int*      bsum    = row_dst + N_NODES + 8;                       // 32
  float*    peW     = (float*)(bsum + 32);                         // 64*128
  float*    a_src   = peW + 64 * 128;                              // N*4
  float*    a_dst   = a_src + (size_t)N_NODES * 4;                 // N*4
  unsigned* xh      = (unsigned*)(a_dst + (size_t)N_NODES * 4);    // N*64 (bf16x2)
  unsigned* bbuf    = xh + (size_t)N_NODES * 64;                   // NB*BCAP
  int*      lst     = (int*)(bbuf + (size_t)NB * BCAP);            // E

  const int B = 256;

  hipMemsetAsync(cnt_nt, 0, ((size_t)N_NODES * 16 + 512) * sizeof(int), stream);
  k_prep<<<1, B, 0, stream>>>(pe, W, peW);
  k_histA<<<HIST_BLOCKS, B, 0, stream>>>(ei, et, cnt_nt, btail, bbuf);
  k_passB_count<<<NB, B, 0, stream>>>(bbuf, btail, cnt_dst);
  k_scan1<<<SCAN_BLOCKS, B, 0, stream>>>(cnt_dst, bsum);
  k_scan2<<<SCAN_BLOCKS, B, 0, stream>>>(cnt_dst, bsum, row_dst);
  k_passB_write<<<NB, B, 0, stream>>>(bbuf, btail, row_dst, lst);
  k_gemm_fused<<<ceil_div(N_NODES, GROWS), B, 0, stream>>>(x, cnt_nt, W, peW,
                                                           att_s, att_d,
                                                           a_src, a_dst, xh);
  k_aggregate<<<ceil_div(N_NODES * 64, B), B, 0, stream>>>(row_dst, lst, a_src, a_dst,
                                                           xh, bias, out);
}

// Round 7
// 149.346 us; speedup vs baseline: 3.2200x; 1.3025x over previous
//
#include <hip/hip_runtime.h>
#include <cstdint>
#include <cstddef>

#define N_NODES 50000
#define N_EDGES 800000
#define IN_CH   64
#define OC      128   // HEADS*OUT_CH
#define HEADS   4
#define CH      32    // OUT_CH

#define NB      391        // dst buckets: 128 nodes each (d>>7)
#define BCAP    2560       // per-bucket capacity (mean 2046, +11 sigma)
#define EPB     4096       // edges per histA block (256 threads x 16)
#define HIST_BLOCKS ((N_EDGES + EPB - 1) / EPB)   // 196

#define SCAN_ITEMS  2048
#define SCAN_BLOCKS ((N_NODES + SCAN_ITEMS - 1) / SCAN_ITEMS)  // 25

typedef __attribute__((ext_vector_type(8))) short short8;   // 8 bf16 (4 VGPRs)
typedef __attribute__((ext_vector_type(4))) float f32x4;

static inline int ceil_div(int a, int b){ return (a + b - 1) / b; }

__device__ __forceinline__ float lrelu(float x){ return fmaxf(x, 0.2f * x); }

__device__ __forceinline__ unsigned pack_bf16(float x, float y){
  unsigned ux = __float_as_uint(x), uy = __float_as_uint(y);
  ux += 0x7FFFu + ((ux >> 16) & 1u);
  uy += 0x7FFFu + ((uy >> 16) & 1u);
  return (ux >> 16) | (uy & 0xFFFF0000u);   // low16 = x, high16 = y
}

// ---- K1: cnt_nt atomics + block-aggregated bucket scatter ----
// entry = (b<<23) | (doff<<16) | src   (b<512, doff<128, src<65536)
__global__ __launch_bounds__(256) void k_histA(const int* __restrict__ ei,
                                               const int* __restrict__ et,
                                               unsigned* __restrict__ cnt_nt,
                                               int* __restrict__ btail,
                                               unsigned* __restrict__ bbuf){
  __shared__ int cnt[NB + 1];
  __shared__ int pos[NB + 1];
  int tid = threadIdx.x;
  for (int i = tid; i <= NB; i += 256){ cnt[i] = 0; }
  __syncthreads();

  int e0 = blockIdx.x * EPB;
  unsigned ent[16];
  #pragma unroll
  for (int j = 0; j < 16; ++j){
    int e = e0 + j * 256 + tid;
    ent[j] = 0xFFFFFFFFu;
    if (e < N_EDGES){
      int s = ei[e], d = ei[N_EDGES + e], t = et[e];
      atomicAdd(&cnt_nt[(size_t)s * 16 + (t >> 2)], 1u << (8 * (t & 3)));
      int b = d >> 7;
      ent[j] = ((unsigned)b << 23) | ((unsigned)(d & 127) << 16) | (unsigned)s;
      atomicAdd(&cnt[b], 1);
    }
  }
  __syncthreads();
  for (int i = tid; i < NB; i += 256){
    int c = cnt[i];
    pos[i] = c ? atomicAdd(&btail[i], c) : 0;
  }
  __syncthreads();
  #pragma unroll
  for (int j = 0; j < 16; ++j){
    if (ent[j] != 0xFFFFFFFFu){
      int b = ent[j] >> 23;
      int p = atomicAdd(&pos[b], 1);
      if (p < BCAP) bbuf[(size_t)b * BCAP + p] = ent[j];
    }
  }
}

// ---- per-bucket node-degree counts ----
__global__ __launch_bounds__(256) void k_passB_count(const unsigned* __restrict__ bbuf,
                                                     const int* __restrict__ btail,
                                                     int* __restrict__ cnt_dst){
  int b = blockIdx.x, tid = threadIdx.x;
  int d0 = b << 7;
  int nn = min(128, N_NODES - d0);
  __shared__ int c[128];
  if (tid < 128) c[tid] = 0;
  __syncthreads();
  int cnt_b = min(btail[b], BCAP);
  for (int i = tid; i < cnt_b; i += 256){
    unsigned ent = bbuf[(size_t)b * BCAP + i];
    atomicAdd(&c[(ent >> 16) & 127], 1);
  }
  __syncthreads();
  if (tid < nn) cnt_dst[d0 + tid] = c[tid];
}

// ---- scan phase 1 ----
__global__ __launch_bounds__(256) void k_scan1(const int* __restrict__ cnt,
                                               int* __restrict__ bsum){
  int blk = blockIdx.x, tid = threadIdx.x;
  int base = blk * SCAN_ITEMS;
  int s = 0;
  #pragma unroll
  for (int j = 0; j < 8; ++j){
    int i = base + j * 256 + tid;
    if (i < N_NODES) s += cnt[i];
  }
  __shared__ int sbuf[256];
  sbuf[tid] = s; __syncthreads();
  for (int off = 128; off > 0; off >>= 1){
    if (tid < off) sbuf[tid] += sbuf[tid + off];
    __syncthreads();
  }
  if (tid == 0) bsum[blk] = sbuf[0];
}

// ---- scan phase 2: row_dst (exclusive at i+1) ----
__global__ __launch_bounds__(256) void k_scan2(const int* __restrict__ cnt,
                                               const int* __restrict__ bsum,
                                               int* __restrict__ row){
  int blk = blockIdx.x, tid = threadIdx.x;
  int base = blk * SCAN_ITEMS + tid * 8;

  __shared__ int sboff;
  if (tid == 0){
    int b = 0;
    for (int q = 0; q < blk; ++q) b += bsum[q];
    sboff = b;
  }
  int v[8];
  #pragma unroll
  for (int j = 0; j < 8; ++j){
    int i = base + j;
    v[j] = (i < N_NODES) ? cnt[i] : 0;
  }
  int pre[8]; int run = 0;
  #pragma unroll
  for (int j = 0; j < 8; ++j){ pre[j] = run; run += v[j]; }

  __shared__ int sbuf[256];
  sbuf[tid] = run; __syncthreads();
  for (int off = 1; off < 256; off <<= 1){
    int t = (tid >= off) ? sbuf[tid - off] : 0;
    __syncthreads();
    sbuf[tid] += t;
    __syncthreads();
  }
  int toff = sbuf[tid] - run;
  int boff = sboff;
  #pragma unroll
  for (int j = 0; j < 8; ++j){
    int i = base + j;
    if (i < N_NODES) row[i + 1] = boff + toff + pre[j] + v[j];
  }
  if (blk == 0 && tid == 0) row[0] = 0;
}

// ---- bucket -> final CSR list ----
__global__ __launch_bounds__(256) void k_passB_write(const unsigned* __restrict__ bbuf,
                                                     const int* __restrict__ btail,
                                                     const int* __restrict__ row,
                                                     int* __restrict__ lst){
  int b = blockIdx.x, tid = threadIdx.x;
  int d0 = b << 7;
  int nn = min(128, N_NODES - d0);
  __shared__ int cur[128];
  __shared__ int g0;
  if (tid == 0) g0 = row[d0];
  __syncthreads();
  int base0 = g0;
  if (tid < nn) cur[tid] = row[d0 + tid] - base0;
  __syncthreads();
  int cnt_b = min(btail[b], BCAP);
  for (int i = tid; i < cnt_b; i += 256){
    unsigned ent = bbuf[(size_t)b * BCAP + i];
    int doff = (ent >> 16) & 127;
    int src  = ent & 0xFFFF;
    int p = atomicAdd(&cur[doff], 1);
    lst[base0 + p] = src;
  }
}

// ---- k_prep: B = [W ; pe@W] (128x128) -> bf16, packed in MFMA B-frag order ----
// Bh u32 index o: j2 = o&3, l = (o>>2)&63, kk = (o>>8)&3, nt = o>>10.
// element pair: k = kk*32 + (l>>4)*8 + 2*j2, n = nt*16 + (l&15); val = B[k][n], B[k+1][n].
__global__ __launch_bounds__(256) void k_prep(const float* __restrict__ pe,
                                              const float* __restrict__ W,
                                              unsigned* __restrict__ Bh){
  __shared__ float sPe[64 * 64];    // 16 KB
  __shared__ float sPeW[64 * 128];  // 32 KB
  int tid = threadIdx.x;
  for (int i = tid; i < 64 * 64 / 4; i += 256)
    ((float4*)sPe)[i] = ((const float4*)pe)[i];
  __syncthreads();
  int c = tid & 127, rb = tid >> 7;
  for (int k = 0; k < 32; ++k){
    int t = rb + 2 * k;
    float a = 0.f;
    #pragma unroll
    for (int i = 0; i < 64; ++i) a += sPe[t * 64 + i] * W[i * 128 + c];
    sPeW[t * 128 + c] = a;
  }
  __syncthreads();
  for (int o = tid; o < 8192; o += 256){
    int j2 = o & 3, l = (o >> 2) & 63, kk = (o >> 8) & 3, nt = o >> 10;
    int k = kk * 32 + (l >> 4) * 8 + 2 * j2;
    int n = nt * 16 + (l & 15);
    float v0 = (k     < 64) ? W[k * 128 + n]       : sPeW[(k - 64) * 128 + n];
    float v1 = (k + 1 < 64) ? W[(k + 1) * 128 + n] : sPeW[(k + 1 - 64) * 128 + n];
    Bh[o] = pack_bf16(v0, v1);
  }
}

// ---- MFMA GEMM: xl = [x | cnt] @ [W ; peW], 64 rows/block, 4 waves ----
// Emits a_src/a_dst (f32 dots via shfl) + xh (bf16x2). No f32 xl materialized.
#define GEMM_ROWS 64
__global__ __launch_bounds__(256) void k_gemm_mfma(const float* __restrict__ x,
                                                   const unsigned* __restrict__ cnt_nt,
                                                   const unsigned* __restrict__ Bh,
                                                   const float* __restrict__ att_s,
                                                   const float* __restrict__ att_d,
                                                   float* __restrict__ a_src,
                                                   float* __restrict__ a_dst,
                                                   unsigned* __restrict__ xh){
  __shared__ unsigned sA[4096];   // 64 rows x 128 k bf16, XOR-swizzled, 16 KB
  __shared__ unsigned sB[8192];   // frag-packed B, 32 KB
  int tid = threadIdx.x;
  int row0 = blockIdx.x * GEMM_ROWS;

  // stage B (linear copy; Bh already frag-ordered)
  {
    const uint4* srcp = (const uint4*)Bh;
    uint4* dstp = (uint4*)sB;
    #pragma unroll
    for (int i = 0; i < 8; ++i) dstp[tid + i * 256] = srcp[tid + i * 256];
  }
  // stage A: thread (r = tid>>2, q = tid&3); bytes [q*32, q*32+32) of row r (x part)
  {
    int r = tid >> 2, q = tid & 3;
    int n = row0 + r;
    unsigned swz = (unsigned)((r & 7) << 4);
    // x part -> k 0..63 (bytes 0..127)
    float4 xv[4];
    if (n < N_NODES){
      const float4* xr = (const float4*)(x + (size_t)n * 64);
      #pragma unroll
      for (int i = 0; i < 4; ++i) xv[i] = xr[q * 4 + i];
    } else {
      #pragma unroll
      for (int i = 0; i < 4; ++i) xv[i] = make_float4(0.f, 0.f, 0.f, 0.f);
    }
    unsigned pk[8];
    #pragma unroll
    for (int i = 0; i < 4; ++i){
      pk[2 * i]     = pack_bf16(xv[i].x, xv[i].y);
      pk[2 * i + 1] = pack_bf16(xv[i].z, xv[i].w);
    }
    unsigned b0 = (unsigned)(r * 256 + q * 32);
    *(uint4*)(sA + (((b0)      ^ swz) >> 2)) = make_uint4(pk[0], pk[1], pk[2], pk[3]);
    *(uint4*)(sA + (((b0 + 16) ^ swz) >> 2)) = make_uint4(pk[4], pk[5], pk[6], pk[7]);
    // cnt part -> k 64..127 (bytes 128..255)
    unsigned cw[4];
    if (n < N_NODES){
      uint4 cv = ((const uint4*)(cnt_nt + (size_t)n * 16))[q];
      cw[0] = cv.x; cw[1] = cv.y; cw[2] = cv.z; cw[3] = cv.w;
    } else { cw[0] = cw[1] = cw[2] = cw[3] = 0; }
    unsigned pc[8];
    #pragma unroll
    for (int i = 0; i < 4; ++i){
      unsigned v = cw[i];
      pc[2 * i]     = pack_bf16((float)(v & 0xFFu), (float)((v >> 8) & 0xFFu));
      pc[2 * i + 1] = pack_bf16((float)((v >> 16) & 0xFFu), (float)(v >> 24));
    }
    unsigned b1 = (unsigned)(r * 256 + 128 + q * 32);
    *(uint4*)(sA + (((b1)      ^ swz) >> 2)) = make_uint4(pc[0], pc[1], pc[2], pc[3]);
    *(uint4*)(sA + (((b1 + 16) ^ swz) >> 2)) = make_uint4(pc[4], pc[5], pc[6], pc[7]);
  }
  __syncthreads();

  int wid = tid >> 6, l = tid & 63;
  int c15 = l & 15, kq = l >> 4;
  int arow = wid * 16 + c15;
  f32x4 acc[8];
  #pragma unroll
  for (int nt = 0; nt < 8; ++nt) acc[nt] = (f32x4){0.f, 0.f, 0.f, 0.f};

  #pragma unroll
  for (int kk = 0; kk < 4; ++kk){
    unsigned abyte = (unsigned)(arow * 256 + kk * 64 + kq * 16);
    abyte ^= (unsigned)((arow & 7) << 4);
    short8 af = *(const short8*)((const char*)sA + abyte);
    #pragma unroll
    for (int nt = 0; nt < 8; ++nt){
      short8 bf = *(const short8*)(sB + (size_t)((nt * 4 + kk) * 64 + l) * 4);
      acc[nt] = __builtin_amdgcn_mfma_f32_16x16x32_bf16(af, bf, acc[nt], 0, 0, 0);
    }
  }

  // epilogue: C/D layout col = lane&15, row = (lane>>4)*4 + reg
  float asv[8], adv[8];
  #pragma unroll
  for (int nt = 0; nt < 8; ++nt){
    asv[nt] = att_s[nt * 16 + c15];
    adv[nt] = att_d[nt * 16 + c15];
  }
  #pragma unroll
  for (int r = 0; r < 4; ++r){
    int row = row0 + wid * 16 + kq * 4 + r;
    bool valid = row < N_NODES;
    #pragma unroll
    for (int h = 0; h < 4; ++h){
      float ps = acc[2 * h][r] * asv[2 * h] + acc[2 * h + 1][r] * asv[2 * h + 1];
      float pd = acc[2 * h][r] * adv[2 * h] + acc[2 * h + 1][r] * adv[2 * h + 1];
      #pragma unroll
      for (int m = 1; m < 16; m <<= 1){
        ps += __shfl_xor(ps, m);
        pd += __shfl_xor(pd, m);
      }
      if (valid && c15 == 0){
        a_src[row * 4 + h] = ps;
        a_dst[row * 4 + h] = pd;
      }
    }
    #pragma unroll
    for (int nt = 0; nt < 8; ++nt){
      float own = acc[nt][r];
      float nb = __shfl_xor(own, 1);
      if (valid && !(c15 & 1))
        xh[(size_t)row * 64 + nt * 8 + (c15 >> 1)] = pack_bf16(own, nb);
    }
  }
}

// ---- fused aggregate: exp (no max), weighted sum, bias+ELU (wave per node) ----
__global__ __launch_bounds__(256) void k_aggregate(const int* __restrict__ row_dst,
                                                   const int* __restrict__ lst,
                                                   const float* __restrict__ a_src,
                                                   const float* __restrict__ a_dst,
                                                   const unsigned* __restrict__ xh,
                                                   const float* __restrict__ bias,
                                                   float* __restrict__ out){
  int n = (blockIdx.x * blockDim.x + threadIdx.x) >> 6;
  if (n >= N_NODES) return;
  int l = threadIdx.x & 63;
  int h = l >> 4;
  float ad = a_dst[n * 4 + h];

  float w = __expf(lrelu(a_src[n * 4 + h] + ad));
  unsigned uv = xh[(size_t)n * 64 + l];
  float l0 = w, l1 = 0.f;
  float a0x = w * __uint_as_float(uv << 16);
  float a0y = w * __uint_as_float(uv & 0xFFFF0000u);
  float a1x = 0.f, a1y = 0.f;

  int k0 = row_dst[n], k1 = row_dst[n + 1];
  for (int kb = k0; kb < k1; kb += 64){
    int rem = k1 - kb;
    int nk = rem < 64 ? rem : 64;
    int sj = lst[(kb + l < k1) ? kb + l : k1 - 1];
    int sA = __shfl(sj, 0);
    int sB = __shfl(sj, nk > 1 ? 1 : 0);
    unsigned uA = xh[(size_t)sA * 64 + l]; float aA = a_src[sA * 4 + h];
    unsigned uB = xh[(size_t)sB * 64 + l]; float aB = a_src[sB * 4 + h];
    for (int j = 0; j < nk; j += 2){
      int pA = j + 2 < nk ? j + 2 : nk - 1;
      int pB = j + 3 < nk ? j + 3 : nk - 1;
      int sA2 = __shfl(sj, pA);
      int sB2 = __shfl(sj, pB);
      unsigned uA2 = xh[(size_t)sA2 * 64 + l]; float aA2 = a_src[sA2 * 4 + h];
      unsigned uB2 = xh[(size_t)sB2 * 64 + l]; float aB2 = a_src[sB2 * 4 + h];
      float wA = __expf(lrelu(aA + ad));
      l0 += wA;
      a0x = fmaf(wA, __uint_as_float(uA << 16), a0x);
      a0y = fmaf(wA, __uint_as_float(uA & 0xFFFF0000u), a0y);
      if (j + 1 < nk){
        float wB = __expf(lrelu(aB + ad));
        l1 += wB;
        a1x = fmaf(wB, __uint_as_float(uB << 16), a1x);
        a1y = fmaf(wB, __uint_as_float(uB & 0xFFFF0000u), a1y);
      }
      uA = uA2; aA = aA2; uB = uB2; aB = aB2;
    }
  }
  float lsum = l0 + l1;
  float accx = a0x + a1x;
  float accy = a0y + a1y;
  float2 b = ((const float2*)bias)[l];
  float r0 = accx / lsum + b.x;
  float r1 = accy / lsum + b.y;
  float2 o;
  o.x = r0 > 0.f ? r0 : expm1f(r0);
  o.y = r1 > 0.f ? r1 : expm1f(r1);
  ((float2*)out)[(size_t)n * 64 + l] = o;
}

extern "C" void kernel_launch(void* const* d_in, const int* in_sizes, int n_in,
                              void* d_out, int out_size, void* d_ws, size_t ws_size,
                              hipStream_t stream){
  const float* x     = (const float*)d_in[0];
  const int*   ei    = (const int*)d_in[1];   // [2, E]
  const int*   et    = (const int*)d_in[2];   // [E]
  const float* pe    = (const float*)d_in[3];
  const float* W     = (const float*)d_in[4];
  const float* att_s = (const float*)d_in[5];
  const float* att_d = (const float*)d_in[6];
  const float* bias  = (const float*)d_in[7];
  float* out = (float*)d_out;

  // workspace carve-up (4-byte units). [cnt_nt | btail] contiguous -> one memset.
  unsigned* cnt_nt  = (unsigned*)d_ws;                             // N*16 (u8 packed)
  int*      btail   = (int*)(cnt_nt + (size_t)N_NODES * 16);       // NB (pad 512)
  int*      cnt_dst = btail + 512;                                 // N
  int*      row_dst = cnt_dst + N_NODES;                           // N+1 (pad 8)
  int*      bsum    = row_dst + N_NODES + 8;                       // 32
  unsigned* Bh      = (unsigned*)(bsum + 32);                      // 8192 (bf16 B, frag-packed)
  float*    a_src   = (float*)(Bh + 8192);                         // N*4
  float*    a_dst   = a_src + (size_t)N_NODES * 4;                 // N*4
  unsigned* xh      = (unsigned*)(a_dst + (size_t)N_NODES * 4);    // N*64 (bf16x2)
  unsigned* bbuf    = xh + (size_t)N_NODES * 64;                   // NB*BCAP
  int*      lst     = (int*)(bbuf + (size_t)NB * BCAP);            // E

  const int B = 256;

  hipMemsetAsync(cnt_nt, 0, ((size_t)N_NODES * 16 + 512) * sizeof(int), stream);
  k_prep<<<1, B, 0, stream>>>(pe, W, Bh);
  k_histA<<<HIST_BLOCKS, B, 0, stream>>>(ei, et, cnt_nt, btail, bbuf);
  k_passB_count<<<NB, B, 0, stream>>>(bbuf, btail, cnt_dst);
  k_scan1<<<SCAN_BLOCKS, B, 0, stream>>>(cnt_dst, bsum);
  k_scan2<<<SCAN_BLOCKS, B, 0, stream>>>(cnt_dst, bsum, row_dst);
  k_passB_write<<<NB, B, 0, stream>>>(bbuf, btail, row_dst, lst);
  k_gemm_mfma<<<ceil_div(N_NODES, GEMM_ROWS), B, 0, stream>>>(x, cnt_nt, Bh,
                                                              att_s, att_d,
                                                              a_src, a_dst, xh);
  k_aggregate<<<ceil_div(N_NODES * 64, B), B, 0, stream>>>(row_dst, lst, a_src, a_dst,
                                                           xh, bias, out);
}